// Round 11
// baseline (579.074 us; speedup 1.0000x reference)
//
#include <hip/hip_runtime.h>
#include <hip/hip_bf16.h>

// TreeLSTM, 128 perfect binary trees, depth 9, H=256. N=130944 nodes.
//
// R10: (1) s_full eliminated -- epilogues fp32-reduce their 32-j logit slice
// per row (2x shfl_xor across l4) and atomicAdd into pl[N][4] f32 (2MB,
// device-scope); final pass out = pl + lin_b. Saves 134MB round-trip + pass.
// (2) 256-row tiles, 512 threads (8 waves): 2x MFMA per barrier, 2x B-reuse,
// half the blocks; LDS 52KB -> 3 blocks/CU. Same 2-phase __syncthreads loop
// (compiler-managed waits -- proven best R6/R9 vs hand pipelines R7/R8).
//
// ws: Wt[768*256]bf16, Ut[1280*512]bf16, x_bf[65536*256]bf16, pl[N*4]f32,
//     hA,cmA [T*512 rows], hB,cmB [T*256 rows]   (T=128: ~188 MiB)

#define NTREES 128
#define NPT    1023
#define HS     256
#define NNODES (NTREES * NPT)
#define NL     (NTREES * 512)

typedef __hip_bfloat16 bf16;
typedef unsigned short us8 __attribute__((ext_vector_type(8)));
typedef unsigned short us4 __attribute__((ext_vector_type(4)));
typedef short bf16x8 __attribute__((ext_vector_type(8)));
typedef float f32x4 __attribute__((ext_vector_type(4)));

typedef __attribute__((address_space(1))) const void gvoid;
typedef __attribute__((address_space(3))) void svoid;
#define GLD16(gp, lp) \
    __builtin_amdgcn_global_load_lds((gvoid*)(gp), (svoid*)(lp), 16, 0, 0)

__device__ __forceinline__ float bits2f(unsigned short b) {
    return __uint_as_float(((unsigned)b) << 16);
}
__device__ __forceinline__ unsigned short f2bits(float x) {
    bf16 h = __float2bfloat16(x);
    return *reinterpret_cast<unsigned short*>(&h);
}
__device__ __forceinline__ float fsigm(float x) {
    return __builtin_amdgcn_rcpf(1.0f + __expf(-x));
}
__device__ __forceinline__ float ftanh(float x) {
    return 1.0f - 2.0f * __builtin_amdgcn_rcpf(1.0f + __expf(2.0f * x));
}

// ---------------------------------------------------------------------------
// prep_all: [0,PREPB) weight transpose; [PREPB,+NL/4) gather x_bf;
//           [PREPB+NL/4, +ZB) zero pl.
// ---------------------------------------------------------------------------
#define WT_ELEMS (768 * 256)
#define UT_ELEMS (1280 * 512)
#define PW_ELEMS (WT_ELEMS + UT_ELEMS)            // 851,968
#define PREPB    ((PW_ELEMS + 255) / 256)         // 3329
#define GATB     (NL / 4)                          // 16384
#define ZB       ((NNODES + 255) / 256)            // 512

__global__ __launch_bounds__(256) void prep_all(
    const float* __restrict__ W_iou, const float* __restrict__ U_f_w,
    const float* __restrict__ U_iou,
    const int* __restrict__ wordid, const int* __restrict__ mask,
    const float* __restrict__ emb,
    bf16* __restrict__ Wt, bf16* __restrict__ Ut, bf16* __restrict__ x_bf,
    float* __restrict__ pl)
{
    if (blockIdx.x < PREPB) {
        const int i = blockIdx.x * 256 + threadIdx.x;
        if (i < WT_ELEMS) {
            const int n = i >> 8, k = i & 255;
            Wt[i] = __float2bfloat16(W_iou[k * 768 + n]);
        } else if (i < PW_ELEMS) {
            const int j = i - WT_ELEMS;
            const int n = j >> 9, k = j & 511;
            const float v = (n < 512) ? U_f_w[k * 512 + n]
                                      : U_iou[k * 768 + (n - 512)];
            Ut[j] = __float2bfloat16(v);
        }
        return;
    }
    if (blockIdx.x < PREPB + GATB) {
        const int wave = threadIdx.x >> 6, lane = threadIdx.x & 63;
        const int gr   = (blockIdx.x - PREPB) * 4 + wave;
        const int node = (gr >> 9) * NPT + 511 + (gr & 511);
        const int j0   = lane * 4;
        us4 v;
        if (mask[node]) {
            const float4 f = *(const float4*)(emb + (long)wordid[node] * HS + j0);
            v[0] = f2bits(f.x); v[1] = f2bits(f.y);
            v[2] = f2bits(f.z); v[3] = f2bits(f.w);
        } else {
            v[0] = v[1] = v[2] = v[3] = 0;
        }
        *(us4*)(x_bf + (long)gr * HS + j0) = v;
        return;
    }
    const int i = (blockIdx.x - PREPB - GATB) * 256 + threadIdx.x;  // node idx
    if (i < NNODES) *(f32x4*)(pl + (long)i * 4) = (f32x4){0.f, 0.f, 0.f, 0.f};
}

// ---------------------------------------------------------------------------
// Fused leaf. 256 rows x (32j x 3 gates), 512 thr / 8 waves, 2-phase loop.
// ---------------------------------------------------------------------------
__global__ __launch_bounds__(512) void leaf_fused(
    const bf16* __restrict__ x_bf, const bf16* __restrict__ Wt,
    const float* __restrict__ b_iou, const float* __restrict__ lin_w,
    bf16* __restrict__ h_s, bf16* __restrict__ cm_s,
    float* __restrict__ pl, const int tree0)
{
    __shared__ __align__(16) short a_s[2][256 * 32];
    __shared__ __align__(16) short b_s[2][96 * 32];
    const int t    = threadIdx.x;
    const int bm0  = blockIdx.x * 256;
    const int c0   = blockIdx.y * 32;
    const int lane = t & 63, wave = t >> 6;
    const int l4a = lane >> 2, k8 = (lane & 3) * 8;

    const bf16* aSrc[2];
    #pragma unroll
    for (int q = 0; q < 2; ++q) {
        const int row = (wave * 2 + q) * 16 + l4a;     // 0..255
        aSrc[q] = x_bf + (long)(tree0 * 512 + bm0 + row) * HS + k8;
    }
    const int bCnt = (wave < 6) ? 1 : 0;
    const bf16* bSrc0;
    {
        int rb = wave * 16 + l4a;
        if (rb > 95) rb = 95;
        const int g = rb >> 5, jl = rb & 31;
        bSrc0 = Wt + (long)(g * 256 + c0 + jl) * 256 + k8;
    }

    const int wr = wave >> 1, wc = wave & 1;
    const int fr = lane & 15, l4 = lane >> 4;

    f32x4 acc[4][3];
    #pragma unroll
    for (int i = 0; i < 4; ++i)
        #pragma unroll
        for (int g = 0; g < 3; ++g) acc[i][g] = (f32x4){0.f, 0.f, 0.f, 0.f};

    auto stage = [&](int buf, int kt) {
        #pragma unroll
        for (int q = 0; q < 2; ++q)
            GLD16(aSrc[q] + kt, &a_s[buf][(wave * 2 + q) * 512]);
        if (bCnt) GLD16(bSrc0 + kt, &b_s[buf][wave * 512]);
    };

    stage(0, 0);
    __syncthreads();
    int cur = 0;
    for (int kt = 0; kt < 256; kt += 32) {
        const int nk = kt + 32;
        if (nk < 256) stage(cur ^ 1, nk);
        bf16x8 af[4], bg[3];
        #pragma unroll
        for (int i = 0; i < 4; ++i)
            af[i] = *(const bf16x8*)&a_s[cur][(wr * 64 + i * 16 + fr) * 32 + l4 * 8];
        #pragma unroll
        for (int g = 0; g < 3; ++g)
            bg[g] = *(const bf16x8*)&b_s[cur][(g * 32 + wc * 16 + fr) * 32 + l4 * 8];
        #pragma unroll
        for (int i = 0; i < 4; ++i)
            #pragma unroll
            for (int g = 0; g < 3; ++g)
                acc[i][g] = __builtin_amdgcn_mfma_f32_16x16x32_bf16(
                    bg[g], af[i], acc[i][g], 0, 0, 0);   // swapped: j in reg dim
        __syncthreads();
        cur ^= 1;
    }

    // Epilogue: lane owns row r (fr), 4 consecutive j (reg q).
    const int j0 = c0 + wc * 16 + l4 * 4;
    const float4 bi4 = *(const float4*)(b_iou + j0);
    const float4 bo4 = *(const float4*)(b_iou + 256 + j0);
    const float4 bu4 = *(const float4*)(b_iou + 512 + j0);
    #pragma unroll
    for (int i = 0; i < 4; ++i) {
        const int r    = bm0 + wr * 64 + i * 16 + fr;
        const int gr   = tree0 * 512 + r;
        const int node = (gr >> 9) * NPT + 511 + (gr & 511);
        us4 sh; us8 scm;
        float p0 = 0.f, p1 = 0.f, p2 = 0.f, p3 = 0.f;
        #pragma unroll
        for (int q = 0; q < 4; ++q) {
            const float iv = fsigm(acc[i][0][q] + ((const float*)&bi4)[q]);
            const float ov = fsigm(acc[i][1][q] + ((const float*)&bo4)[q]);
            const float uv = ftanh(acc[i][2][q] + ((const float*)&bu4)[q]);
            const float cv  = iv * uv;
            const float hv  = ov * ftanh(cv);
            const float mhv = fmaxf(hv, 0.0f);
            sh[q] = f2bits(hv);
            scm[2 * q] = f2bits(cv); scm[2 * q + 1] = f2bits(mhv);
            const float s  = hv + mhv;
            const float4 w = *(const float4*)(lin_w + (j0 + q) * 4);
            p0 += s * w.x; p1 += s * w.y; p2 += s * w.z; p3 += s * w.w;
        }
        *(us4*)(h_s + (long)r * HS + j0)        = sh;
        *(us8*)(cm_s + (long)r * 512 + j0 * 2)  = scm;
        p0 += __shfl_xor(p0, 16); p0 += __shfl_xor(p0, 32);
        p1 += __shfl_xor(p1, 16); p1 += __shfl_xor(p1, 32);
        p2 += __shfl_xor(p2, 16); p2 += __shfl_xor(p2, 32);
        p3 += __shfl_xor(p3, 16); p3 += __shfl_xor(p3, 32);
        if (l4 == 0) {
            float* o = pl + (long)node * 4;
            atomicAdd(o + 0, p0); atomicAdd(o + 1, p1);
            atomicAdd(o + 2, p2); atomicAdd(o + 3, p3);
        }
    }
}

// ---------------------------------------------------------------------------
// Fused level. 256 rows x (32j x 5 gates), 512 thr / 8 waves, 2-phase loop.
// ---------------------------------------------------------------------------
__global__ __launch_bounds__(512) void level_fused(
    const bf16* __restrict__ h_child, const bf16* __restrict__ cm_c,
    const bf16* __restrict__ Ut,
    const float* __restrict__ U_f_b, const float* __restrict__ b_iou,
    const float* __restrict__ lin_w,
    bf16* __restrict__ h_p, bf16* __restrict__ cm_p,
    float* __restrict__ pl, const int lvl, const int M, const int tree0)
{
    __shared__ __align__(16) short a_s[2][256 * 32];
    __shared__ __align__(16) short b_s[2][160 * 32];
    const int t    = threadIdx.x;
    const int bm0  = blockIdx.x * 256;
    const int c0   = blockIdx.y * 32;
    const int lane = t & 63, wave = t >> 6;
    const int l4a = lane >> 2, k8 = (lane & 3) * 8;

    const bf16* aSrc[2];
    #pragma unroll
    for (int q = 0; q < 2; ++q) {
        int p = bm0 + (wave * 2 + q) * 16 + l4a;
        if (p >= M) p = M - 1;
        const int tl  = p >> lvl;
        const int idx = p & ((1 << lvl) - 1);
        const int cls = tl * (2 << lvl) + 2 * idx;
        aSrc[q] = h_child + (long)cls * HS + k8;  // 512 contiguous (2 children)
    }
    // B: 10 GLD16; waves {2,2,1,1,1,1,1,1}.
    const int bCnt   = (wave < 2) ? 2 : 1;
    const int bStart = (wave < 2) ? wave * 2 : wave + 2;
    const bf16* bSrc[2];
    #pragma unroll
    for (int q = 0; q < 2; ++q) {
        int rb = (bStart + q) * 16 + l4a;
        if (rb > 159) rb = 159;
        const int g = rb >> 5, jl = rb & 31;
        bSrc[q] = Ut + (long)(g * 256 + c0 + jl) * 512 + k8;
    }

    const int wr = wave >> 1, wc = wave & 1;
    const int fr = lane & 15, l4 = lane >> 4;

    f32x4 acc[4][5];
    #pragma unroll
    for (int i = 0; i < 4; ++i)
        #pragma unroll
        for (int g = 0; g < 5; ++g) acc[i][g] = (f32x4){0.f, 0.f, 0.f, 0.f};

    auto stage = [&](int buf, int kt) {
        #pragma unroll
        for (int q = 0; q < 2; ++q)
            GLD16(aSrc[q] + kt, &a_s[buf][(wave * 2 + q) * 512]);
        #pragma unroll
        for (int q = 0; q < 2; ++q)
            if (q < bCnt) GLD16(bSrc[q] + kt, &b_s[buf][(bStart + q) * 512]);
    };

    stage(0, 0);
    __syncthreads();
    int cur = 0;
    for (int kt = 0; kt < 512; kt += 32) {
        const int nk = kt + 32;
        if (nk < 512) stage(cur ^ 1, nk);
        bf16x8 af[4], bg[5];
        #pragma unroll
        for (int i = 0; i < 4; ++i)
            af[i] = *(const bf16x8*)&a_s[cur][(wr * 64 + i * 16 + fr) * 32 + l4 * 8];
        #pragma unroll
        for (int g = 0; g < 5; ++g)
            bg[g] = *(const bf16x8*)&b_s[cur][(g * 32 + wc * 16 + fr) * 32 + l4 * 8];
        #pragma unroll
        for (int i = 0; i < 4; ++i)
            #pragma unroll
            for (int g = 0; g < 5; ++g)
                acc[i][g] = __builtin_amdgcn_mfma_f32_16x16x32_bf16(
                    bg[g], af[i], acc[i][g], 0, 0, 0);   // swapped: j in reg dim
        __syncthreads();
        cur ^= 1;
    }

    // Epilogue: lane owns row r, 4 consecutive j.
    const int j0 = c0 + wc * 16 + l4 * 4;
    const float4 bfl4 = *(const float4*)(U_f_b + j0);
    const float4 bfr4 = *(const float4*)(U_f_b + 256 + j0);
    const float4 bi4  = *(const float4*)(b_iou + j0);
    const float4 bo4  = *(const float4*)(b_iou + 256 + j0);
    const float4 bu4  = *(const float4*)(b_iou + 512 + j0);
    #pragma unroll
    for (int i = 0; i < 4; ++i) {
        const int r  = bm0 + wr * 64 + i * 16 + fr;
        const int rc = r < M ? r : M - 1;
        const int tl   = rc >> lvl;
        const int idx  = rc & ((1 << lvl) - 1);
        const int cls  = tl * (2 << lvl) + 2 * idx;
        const int node = (tree0 + tl) * NPT + (1 << lvl) - 1 + idx;
        const us8 cml = *(const us8*)(cm_c + (long)cls * 512 + j0 * 2);
        const us8 cmr = *(const us8*)(cm_c + (long)(cls + 1) * 512 + j0 * 2);
        us4 sh; us8 scm;
        float p0 = 0.f, p1 = 0.f, p2 = 0.f, p3 = 0.f;
        #pragma unroll
        for (int q = 0; q < 4; ++q) {
            const float flv = fsigm(acc[i][0][q] + ((const float*)&bfl4)[q]);
            const float frv = fsigm(acc[i][1][q] + ((const float*)&bfr4)[q]);
            const float iv  = fsigm(acc[i][2][q] + ((const float*)&bi4)[q]);
            const float ov  = fsigm(acc[i][3][q] + ((const float*)&bo4)[q]);
            const float uv  = ftanh(acc[i][4][q] + ((const float*)&bu4)[q]);
            const float ccl = bits2f(cml[2 * q]), mhl = bits2f(cml[2 * q + 1]);
            const float ccr = bits2f(cmr[2 * q]), mhr = bits2f(cmr[2 * q + 1]);
            const float cv  = iv * uv + flv * ccl + frv * ccr;
            const float hv  = ov * ftanh(cv);
            const float mhv = fmaxf(hv, fmaxf(mhl, mhr));
            sh[q] = f2bits(hv);
            scm[2 * q] = f2bits(cv); scm[2 * q + 1] = f2bits(mhv);
            const float s  = hv + mhv;
            const float4 w = *(const float4*)(lin_w + (j0 + q) * 4);
            p0 += s * w.x; p1 += s * w.y; p2 += s * w.z; p3 += s * w.w;
        }
        p0 += __shfl_xor(p0, 16); p0 += __shfl_xor(p0, 32);
        p1 += __shfl_xor(p1, 16); p1 += __shfl_xor(p1, 32);
        p2 += __shfl_xor(p2, 16); p2 += __shfl_xor(p2, 32);
        p3 += __shfl_xor(p3, 16); p3 += __shfl_xor(p3, 32);
        if (r < M) {
            *(us4*)(h_p + (long)r * HS + j0)       = sh;
            *(us8*)(cm_p + (long)r * 512 + j0 * 2) = scm;
            if (l4 == 0) {
                float* o = pl + (long)node * 4;
                atomicAdd(o + 0, p0); atomicAdd(o + 1, p1);
                atomicAdd(o + 2, p2); atomicAdd(o + 3, p3);
            }
        }
    }
}

// ---------------------------------------------------------------------------
// out = pl + lin_b
// ---------------------------------------------------------------------------
__global__ __launch_bounds__(256) void out_final(
    const float* __restrict__ pl, const float* __restrict__ lin_b,
    float* __restrict__ out)
{
    const int i = blockIdx.x * 256 + threadIdx.x;    // node index
    if (i < NNODES) {
        f32x4 v = *(const f32x4*)(pl + (long)i * 4);
        v[0] += lin_b[0]; v[1] += lin_b[1];
        v[2] += lin_b[2]; v[3] += lin_b[3];
        *(f32x4*)(out + (long)i * 4) = v;
    }
}

// ---------------------------------------------------------------------------
extern "C" void kernel_launch(void* const* d_in, const int* in_sizes, int n_in,
                              void* d_out, int out_size, void* d_ws, size_t ws_size,
                              hipStream_t stream) {
    const int*   wordid = (const int*)d_in[0];
    const int*   mask   = (const int*)d_in[1];
    const float* emb    = (const float*)d_in[2];
    const float* W_iou  = (const float*)d_in[3];
    const float* U_iou  = (const float*)d_in[4];
    const float* U_f_w  = (const float*)d_in[5];
    const float* U_f_b  = (const float*)d_in[6];
    const float* b_iou  = (const float*)d_in[7];
    const float* lin_w  = (const float*)d_in[8];
    const float* lin_b  = (const float*)d_in[9];
    float* out = (float*)d_out;

    const size_t wElems  = (size_t)PW_ELEMS;              // bf16 elems
    const size_t xElems  = (size_t)NL * HS;               // 16,777,216
    const size_t plBytes = (size_t)NNODES * 4 * 4;        // 2,095,104 B
    auto need = [&](int T) -> size_t {
        return (wElems + xElems + (size_t)T * 589824) * 2 + plBytes;
    };
    int T = 8;
    const int cands[4] = {128, 64, 32, 16};
    for (int ci = 0; ci < 4; ++ci) {
        if (need(cands[ci]) <= ws_size) { T = cands[ci]; break; }
    }

    bf16* Wt   = (bf16*)d_ws;
    bf16* Ut   = Wt + WT_ELEMS;
    bf16* x_bf = Ut + UT_ELEMS;
    float* pl  = (float*)(x_bf + xElems);
    bf16* hA   = (bf16*)(pl + (size_t)NNODES * 4);
    bf16* cmA  = hA  + (size_t)T * 512 * HS;
    bf16* hB   = cmA + (size_t)T * 512 * HS * 2;
    bf16* cmB  = hB  + (size_t)T * 256 * HS;

    prep_all<<<PREPB + GATB + ZB, 256, 0, stream>>>(
        W_iou, U_f_w, U_iou, wordid, mask, emb, Wt, Ut, x_bf, pl);

    for (int tree0 = 0; tree0 < NTREES; tree0 += T) {
        leaf_fused<<<dim3(T * 512 / 256, 8), 512, 0, stream>>>(
            x_bf, Wt, b_iou, lin_w, hA, cmA, pl, tree0);
        bool childIsA = true;
        for (int l = 8; l >= 0; --l) {
            bf16 *hc, *cmc, *hp, *cmp;
            if (childIsA) { hc = hA; cmc = cmA; hp = hB; cmp = cmB; }
            else          { hc = hB; cmc = cmB; hp = hA; cmp = cmA; }
            const int M = T << l;
            level_fused<<<dim3((M + 255) / 256, 8), 512, 0, stream>>>(
                hc, cmc, Ut, U_f_b, b_iou, lin_w, hp, cmp, pl, l, M, tree0);
            childIsA = !childIsA;
        }
    }
    out_final<<<(NNODES + 255) / 256, 256, 0, stream>>>(pl, lin_b, out);
}